// Round 16
// baseline (218.262 us; speedup 1.0000x reference)
//
#include <hip/hip_runtime.h>
#include <hip/hip_fp16.h>
#include <math.h>

#define NN 576
#define EPSV 1e-5f
#define PSTR 592   // padded p_lds stride (halfs): 2-way max bank aliasing

typedef _Float16 h2v __attribute__((ext_vector_type(2)));
__device__ __forceinline__ float fdot2f(__half2 a, __half2 b, float c) {
    return __builtin_amdgcn_fdot2(__builtin_bit_cast(h2v, a),
                                  __builtin_bit_cast(h2v, b), c, false);
}
__device__ __forceinline__ __half2 h2minv(__half2 a, __half2 b) {
    return __builtin_bit_cast(__half2,
        __builtin_elementwise_min(__builtin_bit_cast(h2v, a), __builtin_bit_cast(h2v, b)));
}
__device__ __forceinline__ __half2 h2maxv(__half2 a, __half2 b) {
    return __builtin_bit_cast(__half2,
        __builtin_elementwise_max(__builtin_bit_cast(h2v, a), __builtin_bit_cast(h2v, b)));
}

__device__ __forceinline__ float gelu_exact(float x) {
    return 0.5f * x * (1.0f + erff(x * 0.70710678118654752f));
}

// Merged setup: y=0,1 tok transpose (b=y); y=2 wTq; y=3 wT0; y=4 wT1; y=5 wh pack
__global__ void k_setup(const float* __restrict__ x, float* __restrict__ tok,
                        const float* __restrict__ mha_in_w,
                        const float* __restrict__ e1w0, const float* __restrict__ vw0,
                        const float* __restrict__ e1w1, const float* __restrict__ vw1,
                        const float* __restrict__ lnw0, const float* __restrict__ lnb0,
                        const float* __restrict__ e2w0,
                        const float* __restrict__ lnw1, const float* __restrict__ lnb1,
                        const float* __restrict__ e2w1,
                        float* __restrict__ wTq, float* __restrict__ wT0,
                        float* __restrict__ wT1, __half* __restrict__ wh) {
    const int which = blockIdx.y;
    const int idx = blockIdx.x * 256 + threadIdx.x;
    if (which < 2) {
        if (idx < NN * 128) {
            int n = idx >> 7, c = idx & 127;
            tok[(size_t)which * NN * 128 + idx] = x[((size_t)which * 128 + c) * NN + n];
        }
        return;
    }
    if (which == 5) {
        if (idx < 1536) {
            int l = idx / 768, i2 = idx - l * 768;
            const float* lw = l ? lnw1 : lnw0;
            const float* lb = l ? lnb1 : lnb0;
            const float* e2 = l ? e2w1 : e2w0;
            float v;
            if (i2 < 128)      v = lw[i2];
            else if (i2 < 256) v = lb[i2 - 128];
            else               v = e2[i2 - 256];
            wh[idx] = __float2half(v);
        }
        return;
    }
    if (idx >= 49152) return;
    int k = idx / 384, o = idx - k * 384;
    if (which == 2) {
        wTq[idx] = mha_in_w[o * 128 + k];
    } else {
        const float* e1w = (which == 3) ? e1w0 : e1w1;
        const float* vw  = (which == 3) ? vw0  : vw1;
        float v;
        if (o < 128)      v = e1w[o * 256 + k];
        else if (o < 256) v = e1w[(o - 128) * 256 + 128 + k];
        else              v = vw[(o - 256) * 128 + k];
        ((which == 3) ? wT0 : wT1)[idx] = v;
    }
}

// Projection, 1 row/block (1152 blocks): chunks 0,1 -> half into the row's
// first 512B; chunk 2 (V) fp32 at floats 256..383. CENTER: per-row mean
// removal of chunks 0,1 (bias included).
template<bool CENTER>
__global__ __launch_bounds__(384) void k_gemmT(
    const float* __restrict__ A, const float* __restrict__ wT,
    const float* __restrict__ b0, const float* __restrict__ b1, const float* __restrict__ b2,
    float* __restrict__ out)
{
    const int t = threadIdx.x;
    const int r0 = blockIdx.x;
    __shared__ float a_s[132];
    if (t < 32)
        *(float4*)&a_s[t * 4] = *(const float4*)(A + (size_t)r0 * 128 + t * 4);
    __syncthreads();
    float acc0 = 0.f;
    #pragma unroll 8
    for (int k = 0; k < 128; ++k)
        acc0 += a_s[k] * wT[(size_t)k * 384 + t];
    const float* bp = (t < 128) ? b0 : ((t < 256) ? b1 : b2);
    float bv = bp ? bp[t & 127] : 0.f;
    acc0 += bv;

    if (CENTER) {
        __shared__ float redc[6];
        const int wv = t >> 6, ln = t & 63;
        float x0 = acc0;
        #pragma unroll
        for (int off = 32; off > 0; off >>= 1) x0 += __shfl_xor(x0, off);
        if (ln == 0) redc[wv] = x0;
        __syncthreads();
        if (t < 256) {
            const int ch = t >> 7;   // 0 or 1
            acc0 -= (redc[2 * ch] + redc[2 * ch + 1]) * (1.0f / 128.0f);
        }
    }
    if (t < 256)
        ((__half*)(out + (size_t)r0 * 384))[t] = __float2half(acc0);
    else
        out[(size_t)r0 * 384 + t] = acc0;
}

// MHA scores via fdot2 on half q|k: one thread per (i,j), 8 heads.
__global__ __launch_bounds__(256) void k_score(
    const float* __restrict__ qkv, __half* __restrict__ sc)
{
    const int jt = blockIdx.x, it = blockIdx.y, b = blockIdx.z;
    const int i0 = it * 16, j0 = jt * 16;
    const int t = threadIdx.x;
    __shared__ __half q_s[16][136], k_s[16][136];
    for (int idx = t; idx < 512; idx += 256) {
        int tile = idx >> 8, r = (idx >> 4) & 15, cq = idx & 15;
        const __half* src = (const __half*)(qkv + (size_t)(b * NN + (tile ? j0 : i0) + r) * 384)
                            + (tile ? 128 : 0) + cq * 8;
        __half* dst = tile ? &k_s[r][cq * 8] : &q_s[r][cq * 8];
        *(uint4*)dst = *(const uint4*)src;
    }
    __syncthreads();
    const int ti = t >> 4, tj = t & 15;
    const uint4* qr = (const uint4*)q_s[ti];
    const uint4* kr = (const uint4*)k_s[tj];
    float acc[8] = {0.f,0.f,0.f,0.f,0.f,0.f,0.f,0.f};
    #pragma unroll
    for (int sstep = 0; sstep < 16; ++sstep) {
        uint4 q4 = qr[sstep], k4 = kr[sstep];
        const __half2* qh = (const __half2*)&q4;
        const __half2* kh = (const __half2*)&k4;
        #pragma unroll
        for (int p = 0; p < 4; ++p)
            acc[sstep >> 1] = fdot2f(qh[p], kh[p], acc[sstep >> 1]);
    }
    __half2 h[4];
    #pragma unroll
    for (int p = 0; p < 4; ++p)
        h[p] = __floats2half2_rn(acc[2 * p] * 0.25f, acc[2 * p + 1] * 0.25f);
    *(uint4*)(sc + ((size_t)(b * NN + i0 + ti) * NN + j0 + tj) * 8) = *(uint4*)h;
}

// Edge MLP fp16: 16x16 tile, 256 threads, 1 pair/thread, poly-tanh gelu.
__global__ __launch_bounds__(256) void k_edge(
    const float* __restrict__ qkv, const __half* __restrict__ wh,
    const float* __restrict__ e2b, __half* __restrict__ ew)
{
    const int jt = blockIdx.x, it = blockIdx.y, b = blockIdx.z;
    const int i0 = it * 16, j0 = jt * 16;
    const int t = threadIdx.x;
    __shared__ __half ua_s[16][136], wb_s[16][136], wh_s[768];

    for (int idx = t; idx < 512; idx += 256) {
        int tile = idx >> 8, r = (idx >> 4) & 15, cq = idx & 15;
        const __half* src = (const __half*)(qkv + (size_t)(b * NN + (tile ? j0 : i0) + r) * 384)
                            + (tile ? 128 : 0) + cq * 8;
        __half* dst = tile ? &wb_s[r][cq * 8] : &ua_s[r][cq * 8];
        *(uint4*)dst = *(const uint4*)src;
    }
    if (t < 96) *(uint4*)&wh_s[t * 8] = *(const uint4*)&wh[t * 8];
    __syncthreads();

    const int ti = t >> 4, tj = t & 15;
    const uint4* uar = (const uint4*)ua_s[ti];
    const uint4* wbr = (const uint4*)wb_s[tj];

    float s2 = 0.f;
    #pragma unroll
    for (int sstep = 0; sstep < 16; ++sstep) {
        uint4 u4 = uar[sstep], w4 = wbr[sstep];
        const __half2* uh = (const __half2*)&u4;
        const __half2* whp = (const __half2*)&w4;
        #pragma unroll
        for (int p = 0; p < 4; ++p) {
            __half2 e = __hadd2(uh[p], whp[p]);
            s2 = fdot2f(e, e, s2);
        }
    }
    const float rstd = rsqrtf(s2 * (1.0f / 128.0f) + EPSV);
    const __half2 rh    = __float2half2_rn(rstd);
    const __half2 c851  = __float2half2_rn(0.851f);
    const __half2 smax  = __float2half2_rn(6.76f);
    const __half2 ca    = __float2half2_rn(0.983447f);
    const __half2 cb    = __float2half2_rn(-0.262113f);
    const __half2 cc    = __float2half2_rn(0.0474374f);
    const __half2 cd    = __float2half2_rn(-0.0032339f);
    const __half2 one2  = __float2half2_rn(1.0f);
    const __half2 none2 = __float2half2_rn(-1.0f);
    const __half2 hlf2  = __float2half2_rn(0.5f);

    float p0 = 0.f, p1 = 0.f, p2 = 0.f, p3 = 0.f;
    #pragma unroll 4
    for (int sstep = 0; sstep < 16; ++sstep) {
        uint4 u4 = uar[sstep], w4 = wbr[sstep];
        uint4 lw4 = *(const uint4*)&wh_s[sstep * 8];
        uint4 lb4 = *(const uint4*)&wh_s[128 + sstep * 8];
        uint4 q04 = *(const uint4*)&wh_s[256 + sstep * 8];
        uint4 q14 = *(const uint4*)&wh_s[384 + sstep * 8];
        uint4 q24 = *(const uint4*)&wh_s[512 + sstep * 8];
        uint4 q34 = *(const uint4*)&wh_s[640 + sstep * 8];
        const __half2* uh  = (const __half2*)&u4;
        const __half2* whp = (const __half2*)&w4;
        const __half2* lwh = (const __half2*)&lw4;
        const __half2* lbh = (const __half2*)&lb4;
        const __half2* q0h = (const __half2*)&q04;
        const __half2* q1h = (const __half2*)&q14;
        const __half2* q2h = (const __half2*)&q24;
        const __half2* q3h = (const __half2*)&q34;
        #pragma unroll
        for (int p = 0; p < 4; ++p) {
            __half2 e   = __hadd2(uh[p], whp[p]);
            __half2 t1  = __hmul2(e, lwh[p]);
            __half2 nrm = __hfma2(t1, rh, lbh[p]);
            __half2 u   = __hmul2(nrm, c851);
            __half2 s   = __hmul2(u, u);
            s  = h2minv(s, smax);
            __half2 f   = __hfma2(s, cd, cc);
            f  = __hfma2(f, s, cb);
            f  = __hfma2(f, s, ca);
            __half2 th  = __hmul2(u, f);
            th = h2minv(th, one2);
            th = h2maxv(th, none2);
            __half2 m   = __hfma2(th, hlf2, hlf2);
            __half2 g   = __hmul2(nrm, m);
            p0 = fdot2f(g, q0h[p], p0);
            p1 = fdot2f(g, q1h[p], p1);
            p2 = fdot2f(g, q2h[p], p2);
            p3 = fdot2f(g, q3h[p], p3);
        }
    }
    __half2 h01 = __floats2half2_rn(p0 + e2b[0], p1 + e2b[1]);
    __half2 h23 = __floats2half2_rn(p2 + e2b[2], p3 + e2b[3]);
    __half* dst = ew + ((size_t)(b * NN + i0 + ti) * NN + j0 + tj) * 4;
    *(__half2*)dst = h01;
    *(__half2*)(dst + 2) = h23;
}

// Aggregate per (b,i): softmax (P cached in LDS) + AV + split-K o-proj + LN.
// FINAL: additionally fuse LN(n2) + concat(attn) + f1 + LN + gelu + f2 +
// token residual, writing the (B,C,H,W) output directly.
template<int NH, bool FINAL>
__global__ __launch_bounds__(256) void k_agg(
    const float* __restrict__ resid, const float* __restrict__ vbuf,
    const __half* __restrict__ sc,
    const float* __restrict__ ow, const float* __restrict__ ob,
    const float* __restrict__ nw, const float* __restrict__ nb,
    float* __restrict__ outp,
    const float* __restrict__ tok, const float* __restrict__ attn,
    const float* __restrict__ n2w, const float* __restrict__ n2b,
    const float* __restrict__ f1w, const float* __restrict__ f1b,
    const float* __restrict__ flnw, const float* __restrict__ flnb,
    const float* __restrict__ f2w, const float* __restrict__ f2b,
    float* __restrict__ finout)
{
    constexpr int GL = 256 / NH;
    constexpr int NE = NN / GL;
    const int bi = blockIdx.x;
    const int b = bi / NN, i = bi - b * NN;
    const int t = threadIdx.x;

    __shared__ __half p_lds[NH * PSTR];
    __shared__ float st_i[NH];
    __shared__ float aggp[8][128];
    __shared__ float agg_s[128];
    __shared__ float op[2][128];
    __shared__ float red1[4], red2[4];
    __shared__ float cat_s[256], gl_s[128];
    __shared__ float red3[4], red4[4], red5[2], red6[2];

    const __half* srow = sc + (size_t)(b * NN + i) * NN * NH;

    // phase 1: per-head max & expsum; cache exp(s-m) in LDS
    {
        const int h = t / GL, jl = t % GL;
        float sv[NE];
        #pragma unroll
        for (int k = 0; k < NE; ++k)
            sv[k] = __half2float(srow[(size_t)(jl + k * GL) * NH + h]);
        float mx = -1e30f;
        #pragma unroll
        for (int k = 0; k < NE; ++k) mx = fmaxf(mx, sv[k]);
        #pragma unroll
        for (int off = GL / 2; off > 0; off >>= 1) mx = fmaxf(mx, __shfl_xor(mx, off));
        float sm = 0.f;
        #pragma unroll
        for (int k = 0; k < NE; ++k) {
            float e = __expf(sv[k] - mx);
            sm += e;
            p_lds[h * PSTR + jl + k * GL] = __float2half(e);
        }
        #pragma unroll
        for (int off = GL / 2; off > 0; off >>= 1) sm += __shfl_xor(sm, off);
        if (jl == 0) st_i[h] = 1.0f / sm;
    }
    __syncthreads();

    // phase 2: AV using cached P
    {
        const int c4 = (t & 31) * 4, jg = t >> 5;
        const int h2 = c4 >> ((NH == 8) ? 4 : 5);
        const float inv2 = st_i[h2];
        float4 acc = {0.f, 0.f, 0.f, 0.f};
        const float* vb = vbuf + 256 + c4;
        const __half* ph = p_lds + h2 * PSTR;
        #pragma unroll 4
        for (int j = jg; j < NN; j += 8) {
            float p = __half2float(ph[j]);
            const float4 v4 = *(const float4*)(vb + (size_t)(b * NN + j) * 384);
            acc.x += p * v4.x; acc.y += p * v4.y; acc.z += p * v4.z; acc.w += p * v4.w;
        }
        acc.x *= inv2; acc.y *= inv2; acc.z *= inv2; acc.w *= inv2;
        *(float4*)&aggp[jg][c4] = acc;
    }
    __syncthreads();
    if (t < 128) {
        float s = 0.f;
        #pragma unroll
        for (int gq = 0; gq < 8; ++gq) s += aggp[gq][t];
        agg_s[t] = s;
    }
    __syncthreads();

    // phase 3: o-proj split-K
    {
        const int c = t & 127, half = t >> 7;
        float o = 0.f;
        const float4* wr = (const float4*)(ow + (size_t)c * 128 + half * 64);
        const float4* ar = (const float4*)(agg_s + half * 64);
        #pragma unroll
        for (int kq = 0; kq < 16; ++kq) {
            float4 w = wr[kq], a = ar[kq];
            o += w.x * a.x + w.y * a.y + w.z * a.z + w.w * a.w;
        }
        op[half][c] = o;
    }
    __syncthreads();
    const size_t row = (size_t)(b * NN + i) * 128;
    float val = 0.f;
    if (t < 128)
        val = op[0][t] + op[1][t] + ob[t] + resid[row + t];

    // phase 4: LN (gn)
    float s1 = val, s2 = val * val;
    #pragma unroll
    for (int off = 32; off > 0; off >>= 1) {
        s1 += __shfl_xor(s1, off);
        s2 += __shfl_xor(s2, off);
    }
    if ((t & 63) == 0) { red1[t >> 6] = s1; red2[t >> 6] = s2; }
    __syncthreads();
    float tot1 = red1[0] + red1[1] + red1[2] + red1[3];
    float tot2 = red2[0] + red2[1] + red2[2] + red2[3];
    float mean = tot1 * (1.0f / 128.0f);
    float var = tot2 * (1.0f / 128.0f) - mean * mean;
    float rstd = rsqrtf(var + EPSV);
    float gval = 0.f;
    if (t < 128) gval = (val - mean) * rstd * nw[t] + nb[t];

    if (!FINAL) {
        if (t < 128) outp[row + t] = gval;
        return;
    }

    // ---- fused k_final ----
    {
        float a1 = gval, a2 = gval * gval;
        #pragma unroll
        for (int off = 32; off > 0; off >>= 1) { a1 += __shfl_xor(a1, off); a2 += __shfl_xor(a2, off); }
        if ((t & 63) == 0) { red3[t >> 6] = a1; red4[t >> 6] = a2; }
    }
    __syncthreads();
    {
        float m2 = (red3[0] + red3[1] + red3[2] + red3[3]) * (1.0f / 128.0f);
        float v2 = (red4[0] + red4[1] + red4[2] + red4[3]) * (1.0f / 128.0f) - m2 * m2;
        float r2 = rsqrtf(v2 + EPSV);
        if (t < 128) {
            cat_s[t] = attn[row + t];
            cat_s[128 + t] = (gval - m2) * r2 * n2w[t] + n2b[t];
        }
    }
    __syncthreads();
    {
        const int o = t & 127, half = t >> 7;
        float f = 0.f;
        const float4* wr = (const float4*)(f1w + (size_t)o * 256 + half * 128);
        const float4* cr = (const float4*)(cat_s + half * 128);
        #pragma unroll
        for (int kq = 0; kq < 32; ++kq) {
            float4 w = wr[kq], c = cr[kq];
            f += w.x * c.x + w.y * c.y + w.z * c.z + w.w * c.w;
        }
        op[half][o] = f;
    }
    __syncthreads();
    float fv = 0.f;
    if (t < 128) fv = op[0][t] + op[1][t] + f1b[t];
    {
        float a1 = fv, a2 = fv * fv;
        #pragma unroll
        for (int off = 32; off > 0; off >>= 1) { a1 += __shfl_xor(a1, off); a2 += __shfl_xor(a2, off); }
        if (t < 128 && (t & 63) == 0) { red5[t >> 6] = a1; red6[t >> 6] = a2; }
    }
    __syncthreads();
    {
        float m3 = (red5[0] + red5[1]) * (1.0f / 128.0f);
        float v3 = (red6[0] + red6[1]) * (1.0f / 128.0f) - m3 * m3;
        float r3 = rsqrtf(v3 + EPSV);
        if (t < 128) {
            float nrm = (fv - m3) * r3 * flnw[t] + flnb[t];
            gl_s[t] = gelu_exact(nrm);
        }
    }
    __syncthreads();
    {
        const int o = t & 127, half = t >> 7;
        float f = 0.f;
        const float4* wr = (const float4*)(f2w + (size_t)o * 128 + half * 64);
        const float4* gr = (const float4*)(gl_s + half * 64);
        #pragma unroll
        for (int kq = 0; kq < 16; ++kq) {
            float4 w = wr[kq], gg = gr[kq];
            f += w.x * gg.x + w.y * gg.y + w.z * gg.z + w.w * gg.w;
        }
        op[half][o] = f;
    }
    __syncthreads();
    if (t < 128)
        finout[((size_t)b * 128 + t) * NN + i] =
            tok[row + t] + op[0][t] + op[1][t] + f2b[t];
}

extern "C" void kernel_launch(void* const* d_in, const int* in_sizes, int n_in,
                              void* d_out, int out_size, void* d_ws, size_t ws_size,
                              hipStream_t stream) {
    const float* x         = (const float*)d_in[0];
    const float* mha_in_b  = (const float*)d_in[2];
    const float* mha_out_w = (const float*)d_in[3];
    const float* mha_out_b = (const float*)d_in[4];
    const float* gv_w[2]  = {(const float*)d_in[5],  (const float*)d_in[17]};
    const float* gv_b[2]  = {(const float*)d_in[6],  (const float*)d_in[18]};
    const float* ge1_w[2] = {(const float*)d_in[7],  (const float*)d_in[19]};
    const float* ge1_b[2] = {(const float*)d_in[8],  (const float*)d_in[20]};
    const float* geln_w[2]= {(const float*)d_in[9],  (const float*)d_in[21]};
    const float* geln_b[2]= {(const float*)d_in[10], (const float*)d_in[22]};
    const float* ge2_w[2] = {(const float*)d_in[11], (const float*)d_in[23]};
    const float* ge2_b[2] = {(const float*)d_in[12], (const float*)d_in[24]};
    const float* go_w[2]  = {(const float*)d_in[13], (const float*)d_in[25]};
    const float* go_b[2]  = {(const float*)d_in[14], (const float*)d_in[26]};
    const float* gn_w[2]  = {(const float*)d_in[15], (const float*)d_in[27]};
    const float* gn_b[2]  = {(const float*)d_in[16], (const float*)d_in[28]};
    const float* n1w = (const float*)d_in[29];
    const float* n1b = (const float*)d_in[30];
    const float* n2w = (const float*)d_in[31];
    const float* n2b = (const float*)d_in[32];
    const float* f1w = (const float*)d_in[33];
    const float* f1b = (const float*)d_in[34];
    const float* flnw = (const float*)d_in[35];
    const float* flnb = (const float*)d_in[36];
    const float* f2w = (const float*)d_in[37];
    const float* f2b = (const float*)d_in[38];

    float* ws     = (float*)d_ws;
    float* tokens = ws;                       // 147456
    float* attn   = tokens + 147456;          // 147456
    float* g      = attn + 147456;            // 147456
    float* qkv    = g + 147456;               // 442368 (fp16 q|k / ua|wb + fp32 V)
    float* wTq    = qkv + 442368;             // 49152
    float* wT0    = wTq + 49152;              // 49152
    float* wT1    = wT0 + 49152;              // 49152
    __half* wh    = (__half*)(wT1 + 49152);   // 1536 (+pad to 2048)
    __half* sc    = wh + 2048;                // 10.6 MB (scores alias edge logits)
    __half* ewh   = sc;

    k_setup<<<dim3(288, 6), 256, 0, stream>>>(x, tokens, (const float*)d_in[1],
        ge1_w[0], gv_w[0], ge1_w[1], gv_w[1],
        geln_w[0], geln_b[0], ge2_w[0],
        geln_w[1], geln_b[1], ge2_w[1],
        wTq, wT0, wT1, wh);

    k_gemmT<false><<<1152, 384, 0, stream>>>(tokens, wTq,
        mha_in_b, mha_in_b + 128, mha_in_b + 256, qkv);
    k_score<<<dim3(36, 36, 2), 256, 0, stream>>>(qkv, sc);
    k_agg<8, false><<<1152, 256, 0, stream>>>(tokens, qkv, sc, mha_out_w, mha_out_b,
        n1w, n1b, attn,
        nullptr, nullptr, nullptr, nullptr, nullptr, nullptr, nullptr, nullptr,
        nullptr, nullptr, nullptr);

    for (int l = 0; l < 2; ++l) {
        const float* xin = (l == 0) ? attn : g;
        const float* wTl = (l == 0) ? wT0 : wT1;
        k_gemmT<true><<<1152, 384, 0, stream>>>(xin, wTl,
            nullptr, ge1_b[l], gv_b[l], qkv);
        k_edge<<<dim3(36, 36, 2), 256, 0, stream>>>(qkv, wh + l * 768,
                                                    ge2_b[l], ewh);
        if (l == 0) {
            k_agg<4, false><<<1152, 256, 0, stream>>>(xin, qkv, ewh, go_w[l], go_b[l],
                gn_w[l], gn_b[l], g,
                nullptr, nullptr, nullptr, nullptr, nullptr, nullptr, nullptr, nullptr,
                nullptr, nullptr, nullptr);
        } else {
            k_agg<4, true><<<1152, 256, 0, stream>>>(xin, qkv, ewh, go_w[l], go_b[l],
                gn_w[l], gn_b[l], nullptr,
                tokens, attn, n2w, n2b, f1w, f1b, flnw, flnb, f2w, f2b,
                (float*)d_out);
        }
    }
}

// Round 17
// 213.067 us; speedup vs baseline: 1.0244x; 1.0244x over previous
//
#include <hip/hip_runtime.h>
#include <hip/hip_fp16.h>
#include <math.h>

#define NN 576
#define EPSV 1e-5f
#define PSTR 592   // padded p_lds stride (halfs): 2-way max bank aliasing

typedef _Float16 h2v __attribute__((ext_vector_type(2)));
__device__ __forceinline__ float fdot2f(__half2 a, __half2 b, float c) {
    return __builtin_amdgcn_fdot2(__builtin_bit_cast(h2v, a),
                                  __builtin_bit_cast(h2v, b), c, false);
}
__device__ __forceinline__ __half2 h2minv(__half2 a, __half2 b) {
    return __builtin_bit_cast(__half2,
        __builtin_elementwise_min(__builtin_bit_cast(h2v, a), __builtin_bit_cast(h2v, b)));
}
__device__ __forceinline__ __half2 h2maxv(__half2 a, __half2 b) {
    return __builtin_bit_cast(__half2,
        __builtin_elementwise_max(__builtin_bit_cast(h2v, a), __builtin_bit_cast(h2v, b)));
}

__device__ __forceinline__ float gelu_exact(float x) {
    return 0.5f * x * (1.0f + erff(x * 0.70710678118654752f));
}

// Merged setup: y=0,1 tok transpose (b=y); y=2 wTq; y=3 wT0; y=4 wT1; y=5 wh pack
__global__ void k_setup(const float* __restrict__ x, float* __restrict__ tok,
                        const float* __restrict__ mha_in_w,
                        const float* __restrict__ e1w0, const float* __restrict__ vw0,
                        const float* __restrict__ e1w1, const float* __restrict__ vw1,
                        const float* __restrict__ lnw0, const float* __restrict__ lnb0,
                        const float* __restrict__ e2w0,
                        const float* __restrict__ lnw1, const float* __restrict__ lnb1,
                        const float* __restrict__ e2w1,
                        float* __restrict__ wTq, float* __restrict__ wT0,
                        float* __restrict__ wT1, __half* __restrict__ wh) {
    const int which = blockIdx.y;
    const int idx = blockIdx.x * 256 + threadIdx.x;
    if (which < 2) {
        if (idx < NN * 128) {
            int n = idx >> 7, c = idx & 127;
            tok[(size_t)which * NN * 128 + idx] = x[((size_t)which * 128 + c) * NN + n];
        }
        return;
    }
    if (which == 5) {
        if (idx < 1536) {
            int l = idx / 768, i2 = idx - l * 768;
            const float* lw = l ? lnw1 : lnw0;
            const float* lb = l ? lnb1 : lnb0;
            const float* e2 = l ? e2w1 : e2w0;
            float v;
            if (i2 < 128)      v = lw[i2];
            else if (i2 < 256) v = lb[i2 - 128];
            else               v = e2[i2 - 256];
            wh[idx] = __float2half(v);
        }
        return;
    }
    if (idx >= 49152) return;
    int k = idx / 384, o = idx - k * 384;
    if (which == 2) {
        wTq[idx] = mha_in_w[o * 128 + k];
    } else {
        const float* e1w = (which == 3) ? e1w0 : e1w1;
        const float* vw  = (which == 3) ? vw0  : vw1;
        float v;
        if (o < 128)      v = e1w[o * 256 + k];
        else if (o < 256) v = e1w[(o - 128) * 256 + 128 + k];
        else              v = vw[(o - 256) * 128 + k];
        ((which == 3) ? wT0 : wT1)[idx] = v;
    }
}

// Projection, 2 rows/block (576 blocks): chunks 0,1 -> half into the row's
// first 512B; chunk 2 (V) fp32 at floats 256..383. CENTER: per-row mean
// removal of chunks 0,1 (bias included).
template<bool CENTER>
__global__ __launch_bounds__(384) void k_gemmT(
    const float* __restrict__ A, const float* __restrict__ wT,
    const float* __restrict__ b0, const float* __restrict__ b1, const float* __restrict__ b2,
    float* __restrict__ out)
{
    const int t = threadIdx.x;
    const int r0 = blockIdx.x * 2;
    __shared__ float a_s[2][132];
    if (t < 64) {
        int r = t >> 5, cq = t & 31;
        *(float4*)&a_s[r][cq * 4] = *(const float4*)(A + (size_t)(r0 + r) * 128 + cq * 4);
    }
    __syncthreads();
    float acc0 = 0.f, acc1 = 0.f;
    #pragma unroll 8
    for (int k = 0; k < 128; ++k) {
        float w = wT[(size_t)k * 384 + t];
        acc0 += a_s[0][k] * w;
        acc1 += a_s[1][k] * w;
    }
    const float* bp = (t < 128) ? b0 : ((t < 256) ? b1 : b2);
    float bv = bp ? bp[t & 127] : 0.f;
    acc0 += bv; acc1 += bv;

    if (CENTER) {
        __shared__ float redc[6][2];
        const int wv = t >> 6, ln = t & 63;
        float x0 = acc0, x1 = acc1;
        #pragma unroll
        for (int off = 32; off > 0; off >>= 1) {
            x0 += __shfl_xor(x0, off);
            x1 += __shfl_xor(x1, off);
        }
        if (ln == 0) { redc[wv][0] = x0; redc[wv][1] = x1; }
        __syncthreads();
        if (t < 256) {
            const int ch = t >> 7;   // 0 or 1
            acc0 -= (redc[2 * ch][0] + redc[2 * ch + 1][0]) * (1.0f / 128.0f);
            acc1 -= (redc[2 * ch][1] + redc[2 * ch + 1][1]) * (1.0f / 128.0f);
        }
    }
    if (t < 256) {
        ((__half*)(out + (size_t)(r0 + 0) * 384))[t] = __float2half(acc0);
        ((__half*)(out + (size_t)(r0 + 1) * 384))[t] = __float2half(acc1);
    } else {
        out[(size_t)(r0 + 0) * 384 + t] = acc0;
        out[(size_t)(r0 + 1) * 384 + t] = acc1;
    }
}

// MHA scores via fdot2 on half q|k: one thread per (i,j), 8 heads.
__global__ __launch_bounds__(256) void k_score(
    const float* __restrict__ qkv, __half* __restrict__ sc)
{
    const int jt = blockIdx.x, it = blockIdx.y, b = blockIdx.z;
    const int i0 = it * 16, j0 = jt * 16;
    const int t = threadIdx.x;
    __shared__ __half q_s[16][136], k_s[16][136];
    for (int idx = t; idx < 512; idx += 256) {
        int tile = idx >> 8, r = (idx >> 4) & 15, cq = idx & 15;
        const __half* src = (const __half*)(qkv + (size_t)(b * NN + (tile ? j0 : i0) + r) * 384)
                            + (tile ? 128 : 0) + cq * 8;
        __half* dst = tile ? &k_s[r][cq * 8] : &q_s[r][cq * 8];
        *(uint4*)dst = *(const uint4*)src;
    }
    __syncthreads();
    const int ti = t >> 4, tj = t & 15;
    const uint4* qr = (const uint4*)q_s[ti];
    const uint4* kr = (const uint4*)k_s[tj];
    float acc[8] = {0.f,0.f,0.f,0.f,0.f,0.f,0.f,0.f};
    #pragma unroll
    for (int sstep = 0; sstep < 16; ++sstep) {
        uint4 q4 = qr[sstep], k4 = kr[sstep];
        const __half2* qh = (const __half2*)&q4;
        const __half2* kh = (const __half2*)&k4;
        #pragma unroll
        for (int p = 0; p < 4; ++p)
            acc[sstep >> 1] = fdot2f(qh[p], kh[p], acc[sstep >> 1]);
    }
    __half2 h[4];
    #pragma unroll
    for (int p = 0; p < 4; ++p)
        h[p] = __floats2half2_rn(acc[2 * p] * 0.25f, acc[2 * p + 1] * 0.25f);
    *(uint4*)(sc + ((size_t)(b * NN + i0 + ti) * NN + j0 + tj) * 8) = *(uint4*)h;
}

// Edge MLP fp16: 16x16 tile, 256 threads, 1 pair/thread, poly-tanh gelu.
__global__ __launch_bounds__(256) void k_edge(
    const float* __restrict__ qkv, const __half* __restrict__ wh,
    const float* __restrict__ e2b, __half* __restrict__ ew)
{
    const int jt = blockIdx.x, it = blockIdx.y, b = blockIdx.z;
    const int i0 = it * 16, j0 = jt * 16;
    const int t = threadIdx.x;
    __shared__ __half ua_s[16][136], wb_s[16][136], wh_s[768];

    for (int idx = t; idx < 512; idx += 256) {
        int tile = idx >> 8, r = (idx >> 4) & 15, cq = idx & 15;
        const __half* src = (const __half*)(qkv + (size_t)(b * NN + (tile ? j0 : i0) + r) * 384)
                            + (tile ? 128 : 0) + cq * 8;
        __half* dst = tile ? &wb_s[r][cq * 8] : &ua_s[r][cq * 8];
        *(uint4*)dst = *(const uint4*)src;
    }
    if (t < 96) *(uint4*)&wh_s[t * 8] = *(const uint4*)&wh[t * 8];
    __syncthreads();

    const int ti = t >> 4, tj = t & 15;
    const uint4* uar = (const uint4*)ua_s[ti];
    const uint4* wbr = (const uint4*)wb_s[tj];

    float s2 = 0.f;
    #pragma unroll
    for (int sstep = 0; sstep < 16; ++sstep) {
        uint4 u4 = uar[sstep], w4 = wbr[sstep];
        const __half2* uh = (const __half2*)&u4;
        const __half2* whp = (const __half2*)&w4;
        #pragma unroll
        for (int p = 0; p < 4; ++p) {
            __half2 e = __hadd2(uh[p], whp[p]);
            s2 = fdot2f(e, e, s2);
        }
    }
    const float rstd = rsqrtf(s2 * (1.0f / 128.0f) + EPSV);
    const __half2 rh    = __float2half2_rn(rstd);
    const __half2 c851  = __float2half2_rn(0.851f);
    const __half2 smax  = __float2half2_rn(6.76f);
    const __half2 ca    = __float2half2_rn(0.983447f);
    const __half2 cb    = __float2half2_rn(-0.262113f);
    const __half2 cc    = __float2half2_rn(0.0474374f);
    const __half2 cd    = __float2half2_rn(-0.0032339f);
    const __half2 one2  = __float2half2_rn(1.0f);
    const __half2 none2 = __float2half2_rn(-1.0f);
    const __half2 hlf2  = __float2half2_rn(0.5f);

    float p0 = 0.f, p1 = 0.f, p2 = 0.f, p3 = 0.f;
    #pragma unroll 4
    for (int sstep = 0; sstep < 16; ++sstep) {
        uint4 u4 = uar[sstep], w4 = wbr[sstep];
        uint4 lw4 = *(const uint4*)&wh_s[sstep * 8];
        uint4 lb4 = *(const uint4*)&wh_s[128 + sstep * 8];
        uint4 q04 = *(const uint4*)&wh_s[256 + sstep * 8];
        uint4 q14 = *(const uint4*)&wh_s[384 + sstep * 8];
        uint4 q24 = *(const uint4*)&wh_s[512 + sstep * 8];
        uint4 q34 = *(const uint4*)&wh_s[640 + sstep * 8];
        const __half2* uh  = (const __half2*)&u4;
        const __half2* whp = (const __half2*)&w4;
        const __half2* lwh = (const __half2*)&lw4;
        const __half2* lbh = (const __half2*)&lb4;
        const __half2* q0h = (const __half2*)&q04;
        const __half2* q1h = (const __half2*)&q14;
        const __half2* q2h = (const __half2*)&q24;
        const __half2* q3h = (const __half2*)&q34;
        #pragma unroll
        for (int p = 0; p < 4; ++p) {
            __half2 e   = __hadd2(uh[p], whp[p]);
            __half2 t1  = __hmul2(e, lwh[p]);
            __half2 nrm = __hfma2(t1, rh, lbh[p]);
            __half2 u   = __hmul2(nrm, c851);
            __half2 s   = __hmul2(u, u);
            s  = h2minv(s, smax);
            __half2 f   = __hfma2(s, cd, cc);
            f  = __hfma2(f, s, cb);
            f  = __hfma2(f, s, ca);
            __half2 th  = __hmul2(u, f);
            th = h2minv(th, one2);
            th = h2maxv(th, none2);
            __half2 m   = __hfma2(th, hlf2, hlf2);
            __half2 g   = __hmul2(nrm, m);
            p0 = fdot2f(g, q0h[p], p0);
            p1 = fdot2f(g, q1h[p], p1);
            p2 = fdot2f(g, q2h[p], p2);
            p3 = fdot2f(g, q3h[p], p3);
        }
    }
    __half2 h01 = __floats2half2_rn(p0 + e2b[0], p1 + e2b[1]);
    __half2 h23 = __floats2half2_rn(p2 + e2b[2], p3 + e2b[3]);
    __half* dst = ew + ((size_t)(b * NN + i0 + ti) * NN + j0 + tj) * 4;
    *(__half2*)dst = h01;
    *(__half2*)(dst + 2) = h23;
}

// Aggregate per (b,i): softmax (P cached in LDS) + AV + split-K o-proj + LN.
// FINAL: additionally fuse LN(n2) + concat(attn) + f1 + LN + gelu + f2 +
// token residual, writing the (B,C,H,W) output directly.
template<int NH, bool FINAL>
__global__ __launch_bounds__(256) void k_agg(
    const float* __restrict__ resid, const float* __restrict__ vbuf,
    const __half* __restrict__ sc,
    const float* __restrict__ ow, const float* __restrict__ ob,
    const float* __restrict__ nw, const float* __restrict__ nb,
    float* __restrict__ outp,
    const float* __restrict__ tok, const float* __restrict__ attn,
    const float* __restrict__ n2w, const float* __restrict__ n2b,
    const float* __restrict__ f1w, const float* __restrict__ f1b,
    const float* __restrict__ flnw, const float* __restrict__ flnb,
    const float* __restrict__ f2w, const float* __restrict__ f2b,
    float* __restrict__ finout)
{
    constexpr int GL = 256 / NH;
    constexpr int NE = NN / GL;
    const int bi = blockIdx.x;
    const int b = bi / NN, i = bi - b * NN;
    const int t = threadIdx.x;

    __shared__ __half p_lds[NH * PSTR];
    __shared__ float st_i[NH];
    __shared__ float aggp[8][128];
    __shared__ float agg_s[128];
    __shared__ float op[2][128];
    __shared__ float red1[4], red2[4];
    __shared__ float cat_s[256], gl_s[128];
    __shared__ float red3[4], red4[4], red5[2], red6[2];

    const __half* srow = sc + (size_t)(b * NN + i) * NN * NH;

    // phase 1: per-head max & expsum; cache exp(s-m) in LDS
    {
        const int h = t / GL, jl = t % GL;
        float sv[NE];
        #pragma unroll
        for (int k = 0; k < NE; ++k)
            sv[k] = __half2float(srow[(size_t)(jl + k * GL) * NH + h]);
        float mx = -1e30f;
        #pragma unroll
        for (int k = 0; k < NE; ++k) mx = fmaxf(mx, sv[k]);
        #pragma unroll
        for (int off = GL / 2; off > 0; off >>= 1) mx = fmaxf(mx, __shfl_xor(mx, off));
        float sm = 0.f;
        #pragma unroll
        for (int k = 0; k < NE; ++k) {
            float e = __expf(sv[k] - mx);
            sm += e;
            p_lds[h * PSTR + jl + k * GL] = __float2half(e);
        }
        #pragma unroll
        for (int off = GL / 2; off > 0; off >>= 1) sm += __shfl_xor(sm, off);
        if (jl == 0) st_i[h] = 1.0f / sm;
    }
    __syncthreads();

    // phase 2: AV using cached P
    {
        const int c4 = (t & 31) * 4, jg = t >> 5;
        const int h2 = c4 >> ((NH == 8) ? 4 : 5);
        const float inv2 = st_i[h2];
        float4 acc = {0.f, 0.f, 0.f, 0.f};
        const float* vb = vbuf + 256 + c4;
        const __half* ph = p_lds + h2 * PSTR;
        #pragma unroll 4
        for (int j = jg; j < NN; j += 8) {
            float p = __half2float(ph[j]);
            const float4 v4 = *(const float4*)(vb + (size_t)(b * NN + j) * 384);
            acc.x += p * v4.x; acc.y += p * v4.y; acc.z += p * v4.z; acc.w += p * v4.w;
        }
        acc.x *= inv2; acc.y *= inv2; acc.z *= inv2; acc.w *= inv2;
        *(float4*)&aggp[jg][c4] = acc;
    }
    __syncthreads();
    if (t < 128) {
        float s = 0.f;
        #pragma unroll
        for (int gq = 0; gq < 8; ++gq) s += aggp[gq][t];
        agg_s[t] = s;
    }
    __syncthreads();

    // phase 3: o-proj split-K
    {
        const int c = t & 127, half = t >> 7;
        float o = 0.f;
        const float4* wr = (const float4*)(ow + (size_t)c * 128 + half * 64);
        const float4* ar = (const float4*)(agg_s + half * 64);
        #pragma unroll
        for (int kq = 0; kq < 16; ++kq) {
            float4 w = wr[kq], a = ar[kq];
            o += w.x * a.x + w.y * a.y + w.z * a.z + w.w * a.w;
        }
        op[half][c] = o;
    }
    __syncthreads();
    const size_t row = (size_t)(b * NN + i) * 128;
    float val = 0.f;
    if (t < 128)
        val = op[0][t] + op[1][t] + ob[t] + resid[row + t];

    // phase 4: LN (gn)
    float s1 = val, s2 = val * val;
    #pragma unroll
    for (int off = 32; off > 0; off >>= 1) {
        s1 += __shfl_xor(s1, off);
        s2 += __shfl_xor(s2, off);
    }
    if ((t & 63) == 0) { red1[t >> 6] = s1; red2[t >> 6] = s2; }
    __syncthreads();
    float tot1 = red1[0] + red1[1] + red1[2] + red1[3];
    float tot2 = red2[0] + red2[1] + red2[2] + red2[3];
    float mean = tot1 * (1.0f / 128.0f);
    float var = tot2 * (1.0f / 128.0f) - mean * mean;
    float rstd = rsqrtf(var + EPSV);
    float gval = 0.f;
    if (t < 128) gval = (val - mean) * rstd * nw[t] + nb[t];

    if (!FINAL) {
        if (t < 128) outp[row + t] = gval;
        return;
    }

    // ---- fused k_final ----
    {
        float a1 = gval, a2 = gval * gval;
        #pragma unroll
        for (int off = 32; off > 0; off >>= 1) { a1 += __shfl_xor(a1, off); a2 += __shfl_xor(a2, off); }
        if ((t & 63) == 0) { red3[t >> 6] = a1; red4[t >> 6] = a2; }
    }
    __syncthreads();
    {
        float m2 = (red3[0] + red3[1] + red3[2] + red3[3]) * (1.0f / 128.0f);
        float v2 = (red4[0] + red4[1] + red4[2] + red4[3]) * (1.0f / 128.0f) - m2 * m2;
        float r2 = rsqrtf(v2 + EPSV);
        if (t < 128) {
            cat_s[t] = attn[row + t];
            cat_s[128 + t] = (gval - m2) * r2 * n2w[t] + n2b[t];
        }
    }
    __syncthreads();
    {
        const int o = t & 127, half = t >> 7;
        float f = 0.f;
        const float4* wr = (const float4*)(f1w + (size_t)o * 256 + half * 128);
        const float4* cr = (const float4*)(cat_s + half * 128);
        #pragma unroll
        for (int kq = 0; kq < 32; ++kq) {
            float4 w = wr[kq], c = cr[kq];
            f += w.x * c.x + w.y * c.y + w.z * c.z + w.w * c.w;
        }
        op[half][o] = f;
    }
    __syncthreads();
    float fv = 0.f;
    if (t < 128) fv = op[0][t] + op[1][t] + f1b[t];
    {
        float a1 = fv, a2 = fv * fv;
        #pragma unroll
        for (int off = 32; off > 0; off >>= 1) { a1 += __shfl_xor(a1, off); a2 += __shfl_xor(a2, off); }
        if (t < 128 && (t & 63) == 0) { red5[t >> 6] = a1; red6[t >> 6] = a2; }
    }
    __syncthreads();
    {
        float m3 = (red5[0] + red5[1]) * (1.0f / 128.0f);
        float v3 = (red6[0] + red6[1]) * (1.0f / 128.0f) - m3 * m3;
        float r3 = rsqrtf(v3 + EPSV);
        if (t < 128) {
            float nrm = (fv - m3) * r3 * flnw[t] + flnb[t];
            gl_s[t] = gelu_exact(nrm);
        }
    }
    __syncthreads();
    {
        const int o = t & 127, half = t >> 7;
        float f = 0.f;
        const float4* wr = (const float4*)(f2w + (size_t)o * 128 + half * 64);
        const float4* gr = (const float4*)(gl_s + half * 64);
        #pragma unroll
        for (int kq = 0; kq < 16; ++kq) {
            float4 w = wr[kq], gg = gr[kq];
            f += w.x * gg.x + w.y * gg.y + w.z * gg.z + w.w * gg.w;
        }
        op[half][o] = f;
    }
    __syncthreads();
    if (t < 128)
        finout[((size_t)b * 128 + t) * NN + i] =
            tok[row + t] + op[0][t] + op[1][t] + f2b[t];
}

extern "C" void kernel_launch(void* const* d_in, const int* in_sizes, int n_in,
                              void* d_out, int out_size, void* d_ws, size_t ws_size,
                              hipStream_t stream) {
    const float* x         = (const float*)d_in[0];
    const float* mha_in_b  = (const float*)d_in[2];
    const float* mha_out_w = (const float*)d_in[3];
    const float* mha_out_b = (const float*)d_in[4];
    const float* gv_w[2]  = {(const float*)d_in[5],  (const float*)d_in[17]};
    const float* gv_b[2]  = {(const float*)d_in[6],  (const float*)d_in[18]};
    const float* ge1_w[2] = {(const float*)d_in[7],  (const float*)d_in[19]};
    const float* ge1_b[2] = {(const float*)d_in[8],  (const float*)d_in[20]};
    const float* geln_w[2]= {(const float*)d_in[9],  (const float*)d_in[21]};
    const float* geln_b[2]= {(const float*)d_in[10], (const float*)d_in[22]};
    const float* ge2_w[2] = {(const float*)d_in[11], (const float*)d_in[23]};
    const float* ge2_b[2] = {(const float*)d_in[12], (const float*)d_in[24]};
    const float* go_w[2]  = {(const float*)d_in[13], (const float*)d_in[25]};
    const float* go_b[2]  = {(const float*)d_in[14], (const float*)d_in[26]};
    const float* gn_w[2]  = {(const float*)d_in[15], (const float*)d_in[27]};
    const float* gn_b[2]  = {(const float*)d_in[16], (const float*)d_in[28]};
    const float* n1w = (const float*)d_in[29];
    const float* n1b = (const float*)d_in[30];
    const float* n2w = (const float*)d_in[31];
    const float* n2b = (const float*)d_in[32];
    const float* f1w = (const float*)d_in[33];
    const float* f1b = (const float*)d_in[34];
    const float* flnw = (const float*)d_in[35];
    const float* flnb = (const float*)d_in[36];
    const float* f2w = (const float*)d_in[37];
    const float* f2b = (const float*)d_in[38];

    float* ws     = (float*)d_ws;
    float* tokens = ws;                       // 147456
    float* attn   = tokens + 147456;          // 147456
    float* g      = attn + 147456;            // 147456
    float* qkv    = g + 147456;               // 442368 (fp16 q|k / ua|wb + fp32 V)
    float* wTq    = qkv + 442368;             // 49152
    float* wT0    = wTq + 49152;              // 49152
    float* wT1    = wT0 + 49152;              // 49152
    __half* wh    = (__half*)(wT1 + 49152);   // 1536 (+pad to 2048)
    __half* sc    = wh + 2048;                // 10.6 MB (scores alias edge logits)
    __half* ewh   = sc;

    k_setup<<<dim3(288, 6), 256, 0, stream>>>(x, tokens, (const float*)d_in[1],
        ge1_w[0], gv_w[0], ge1_w[1], gv_w[1],
        geln_w[0], geln_b[0], ge2_w[0],
        geln_w[1], geln_b[1], ge2_w[1],
        wTq, wT0, wT1, wh);

    k_gemmT<false><<<576, 384, 0, stream>>>(tokens, wTq,
        mha_in_b, mha_in_b + 128, mha_in_b + 256, qkv);
    k_score<<<dim3(36, 36, 2), 256, 0, stream>>>(qkv, sc);
    k_agg<8, false><<<1152, 256, 0, stream>>>(tokens, qkv, sc, mha_out_w, mha_out_b,
        n1w, n1b, attn,
        nullptr, nullptr, nullptr, nullptr, nullptr, nullptr, nullptr, nullptr,
        nullptr, nullptr, nullptr);

    for (int l = 0; l < 2; ++l) {
        const float* xin = (l == 0) ? attn : g;
        const float* wTl = (l == 0) ? wT0 : wT1;
        k_gemmT<true><<<576, 384, 0, stream>>>(xin, wTl,
            nullptr, ge1_b[l], gv_b[l], qkv);
        k_edge<<<dim3(36, 36, 2), 256, 0, stream>>>(qkv, wh + l * 768,
                                                    ge2_b[l], ewh);
        if (l == 0) {
            k_agg<4, false><<<1152, 256, 0, stream>>>(xin, qkv, ewh, go_w[l], go_b[l],
                gn_w[l], gn_b[l], g,
                nullptr, nullptr, nullptr, nullptr, nullptr, nullptr, nullptr, nullptr,
                nullptr, nullptr, nullptr);
        } else {
            k_agg<4, true><<<1152, 256, 0, stream>>>(xin, qkv, ewh, go_w[l], go_b[l],
                gn_w[l], gn_b[l], nullptr,
                tokens, attn, n2w, n2b, f1w, f1b, flnw, flnb, f2w, f2b,
                (float*)d_out);
        }
    }
}